// Round 2
// baseline (348.568 us; speedup 1.0000x reference)
//
#include <hip/hip_runtime.h>

// 4-bit ripple-borrow subtractor.
// A,B: (N,4) float32 with values in {0.0, 1.0}.
// Out: [ diffs (N,4) | borrow (N,1) ] flat float32.
// Index 3 is the LSB (reference loops i = 3..0).
//
// R2: R1 fix — __builtin_nontemporal_store needs a clang vector type, not
// HIP_vector_type<float,4>. Bit-cast through ext_vector_type(4).
// Strategy: 4 rows/thread (8 independent 16B loads in flight, wave-blocked
// indexing keeps every access coalesced) + nontemporal stores so the 168 MB
// write stream doesn't evict input lines from L2/L3.

constexpr int BLOCK = 256;
constexpr int RPT   = 4;   // rows per thread

typedef float v4f __attribute__((ext_vector_type(4)));

__device__ __forceinline__ void sub4(const float4 af, const float4 bf,
                                     float4& r, float& bo)
{
    // Inputs are exactly 0.0f or 1.0f.
    int a0 = (af.x != 0.0f), a1 = (af.y != 0.0f), a2 = (af.z != 0.0f), a3 = (af.w != 0.0f);
    int b0 = (bf.x != 0.0f), b1 = (bf.y != 0.0f), b2 = (bf.z != 0.0f), b3 = (bf.w != 0.0f);

    int bor = 0;
    // i = 3 (LSB)
    int d3 = a3 ^ b3 ^ bor;
    int na = 1 - a3;
    bor = (na & b3) | (na & bor) | (b3 & bor);
    // i = 2
    int d2 = a2 ^ b2 ^ bor;
    na = 1 - a2;
    bor = (na & b2) | (na & bor) | (b2 & bor);
    // i = 1
    int d1 = a1 ^ b1 ^ bor;
    na = 1 - a1;
    bor = (na & b1) | (na & bor) | (b1 & bor);
    // i = 0 (MSB)
    int d0 = a0 ^ b0 ^ bor;
    na = 1 - a0;
    bor = (na & b0) | (na & bor) | (b0 & bor);

    r.x = (float)d0;
    r.y = (float)d1;
    r.z = (float)d2;
    r.w = (float)d3;
    bo  = (float)bor;
}

__global__ __launch_bounds__(BLOCK) void Subtractor4Bit_kernel(
    const float4* __restrict__ A,
    const float4* __restrict__ B,
    float4* __restrict__ res,
    float* __restrict__ borrow_out,
    int n_rows)
{
    int base = blockIdx.x * (BLOCK * RPT) + threadIdx.x;

    if (base + (RPT - 1) * BLOCK < n_rows) {
        // Fast path: all RPT rows valid (always taken for N = 2^23).
        float4 a[RPT], b[RPT];
#pragma unroll
        for (int k = 0; k < RPT; ++k) a[k] = A[base + k * BLOCK];
#pragma unroll
        for (int k = 0; k < RPT; ++k) b[k] = B[base + k * BLOCK];

#pragma unroll
        for (int k = 0; k < RPT; ++k) {
            float4 r; float bo;
            sub4(a[k], b[k], r, bo);
            v4f rv;
            __builtin_memcpy(&rv, &r, sizeof(rv));
            __builtin_nontemporal_store(rv, (v4f*)&res[base + k * BLOCK]);
            __builtin_nontemporal_store(bo, &borrow_out[base + k * BLOCK]);
        }
    } else {
        // Tail path (never taken when n_rows % (BLOCK*RPT) == 0).
        for (int k = 0; k < RPT; ++k) {
            int i = base + k * BLOCK;
            if (i < n_rows) {
                float4 r; float bo;
                sub4(A[i], B[i], r, bo);
                res[i] = r;
                borrow_out[i] = bo;
            }
        }
    }
}

extern "C" void kernel_launch(void* const* d_in, const int* in_sizes, int n_in,
                              void* d_out, int out_size, void* d_ws, size_t ws_size,
                              hipStream_t stream)
{
    const float4* A = (const float4*)d_in[0];
    const float4* B = (const float4*)d_in[1];
    float* out = (float*)d_out;

    int n_rows = in_sizes[0] / 4;              // (N,4) -> N rows
    float4* res = (float4*)out;                // first 4*N floats: diffs
    float* borrow = out + (size_t)n_rows * 4;  // last N floats: borrow

    int rows_per_block = BLOCK * RPT;
    int grid = (n_rows + rows_per_block - 1) / rows_per_block;
    Subtractor4Bit_kernel<<<grid, BLOCK, 0, stream>>>(A, B, res, borrow, n_rows);
}

// Round 3
// 348.039 us; speedup vs baseline: 1.0015x; 1.0015x over previous
//
#include <hip/hip_runtime.h>

// 4-bit ripple-borrow subtractor.
// A,B: (N,4) float32 with values in {0.0, 1.0}.
// Out: [ diffs (N,4) | borrow (N,1) ] flat float32.
// Index 3 is the LSB (reference loops i = 3..0).
//
// R3: nt stores removed (R2 showed identical FETCH/WRITE but 18% slower —
// pure loss on gfx950). Structure switched to the canonical copy-bench
// shape: persistent grid (2048 blocks = 8 blocks/CU, full occupancy),
// grid-stride loop unrolled x4. At any instant the active footprint is
// contiguous 8MB slabs (whole machine covers one stride), unlike R2's
// fragmented per-block 16KB spans.

constexpr int BLOCK  = 256;
constexpr int UNROLL = 4;
constexpr int GRID   = 2048;   // 8 blocks/CU * 256 CUs

__device__ __forceinline__ void sub4(const float4 af, const float4 bf,
                                     float4& r, float& bo)
{
    // Inputs are exactly 0.0f or 1.0f.
    int a0 = (af.x != 0.0f), a1 = (af.y != 0.0f), a2 = (af.z != 0.0f), a3 = (af.w != 0.0f);
    int b0 = (bf.x != 0.0f), b1 = (bf.y != 0.0f), b2 = (bf.z != 0.0f), b3 = (bf.w != 0.0f);

    int bor = 0;
    // i = 3 (LSB)
    int d3 = a3 ^ b3 ^ bor;
    int na = 1 - a3;
    bor = (na & b3) | (na & bor) | (b3 & bor);
    // i = 2
    int d2 = a2 ^ b2 ^ bor;
    na = 1 - a2;
    bor = (na & b2) | (na & bor) | (b2 & bor);
    // i = 1
    int d1 = a1 ^ b1 ^ bor;
    na = 1 - a1;
    bor = (na & b1) | (na & bor) | (b1 & bor);
    // i = 0 (MSB)
    int d0 = a0 ^ b0 ^ bor;
    na = 1 - a0;
    bor = (na & b0) | (na & bor) | (b0 & bor);

    r.x = (float)d0;
    r.y = (float)d1;
    r.z = (float)d2;
    r.w = (float)d3;
    bo  = (float)bor;
}

__global__ __launch_bounds__(BLOCK) void Subtractor4Bit_kernel(
    const float4* __restrict__ A,
    const float4* __restrict__ B,
    float4* __restrict__ res,
    float* __restrict__ borrow_out,
    int n_rows)
{
    const int stride = gridDim.x * BLOCK;
    int i = blockIdx.x * BLOCK + threadIdx.x;

    // Main loop: 4 grid-stride rows per iteration (8 independent loads in
    // flight). For N = 2^23 with GRID=2048: stride = 524288, exactly 4
    // main iterations per thread, tail loop never runs.
    for (; i + (UNROLL - 1) * stride < n_rows; i += UNROLL * stride) {
        float4 a[UNROLL], b[UNROLL];
#pragma unroll
        for (int k = 0; k < UNROLL; ++k) a[k] = A[i + k * stride];
#pragma unroll
        for (int k = 0; k < UNROLL; ++k) b[k] = B[i + k * stride];

#pragma unroll
        for (int k = 0; k < UNROLL; ++k) {
            float4 r; float bo;
            sub4(a[k], b[k], r, bo);
            res[i + k * stride]        = r;
            borrow_out[i + k * stride] = bo;
        }
    }
    // Tail (not taken for N = 2^23).
    for (; i < n_rows; i += stride) {
        float4 r; float bo;
        sub4(A[i], B[i], r, bo);
        res[i] = r;
        borrow_out[i] = bo;
    }
}

extern "C" void kernel_launch(void* const* d_in, const int* in_sizes, int n_in,
                              void* d_out, int out_size, void* d_ws, size_t ws_size,
                              hipStream_t stream)
{
    const float4* A = (const float4*)d_in[0];
    const float4* B = (const float4*)d_in[1];
    float* out = (float*)d_out;

    int n_rows = in_sizes[0] / 4;              // (N,4) -> N rows
    float4* res = (float4*)out;                // first 4*N floats: diffs
    float* borrow = out + (size_t)n_rows * 4;  // last N floats: borrow

    int blocks_needed = (n_rows + BLOCK - 1) / BLOCK;
    int grid = blocks_needed < GRID ? blocks_needed : GRID;
    Subtractor4Bit_kernel<<<grid, BLOCK, 0, stream>>>(A, B, res, borrow, n_rows);
}

// Round 4
// 321.029 us; speedup vs baseline: 1.0858x; 1.0841x over previous
//
#include <hip/hip_runtime.h>

// 4-bit ripple-borrow subtractor, one thread per row (R0 shape — best measured).
// A,B: (N,4) float32 with values in {0.0, 1.0}.
// Out: [ diffs (N,4) | borrow (N,1) ] flat float32.
// Index 3 is the LSB (reference loops i = 3..0).
//
// R4: R0 + NONTEMPORAL LOADS. Theory: inputs (268 MB) thrash the 256 MB MALL
// every iteration (FETCH = exactly 50% of input = partial adaptive retention);
// the fill/evict churn is the ~3.75 TB/s delivered-BW choke, not HBM (2.4x
// headroom). NT loads skip MALL allocation -> pure streaming reads.
// Diagnostic signature: FETCH_SIZE should ~double to ~262 MB.
// R2/R3 lesson: MLP stacking is useless (queues already saturated); keep the
// flat one-row-per-thread shape that measured best (113 us).

constexpr int BLOCK = 256;

typedef float v4f __attribute__((ext_vector_type(4)));

__global__ __launch_bounds__(BLOCK) void Subtractor4Bit_kernel(
    const float* __restrict__ A,
    const float* __restrict__ B,
    float* __restrict__ res,
    float* __restrict__ borrow_out,
    int n_rows)
{
    int i = blockIdx.x * BLOCK + threadIdx.x;
    if (i >= n_rows) return;

    v4f a = __builtin_nontemporal_load((const v4f*)A + i);
    v4f b = __builtin_nontemporal_load((const v4f*)B + i);

    // Convert to 0/1 ints (inputs are exactly 0.0f or 1.0f).
    int a0 = (a[0] != 0.0f), a1 = (a[1] != 0.0f), a2 = (a[2] != 0.0f), a3 = (a[3] != 0.0f);
    int b0 = (b[0] != 0.0f), b1 = (b[1] != 0.0f), b2 = (b[2] != 0.0f), b3 = (b[3] != 0.0f);

    int bor = 0;
    // i = 3 (LSB)
    int d3 = a3 ^ b3 ^ bor;
    int na = 1 - a3;
    bor = (na & b3) | (na & bor) | (b3 & bor);
    // i = 2
    int d2 = a2 ^ b2 ^ bor;
    na = 1 - a2;
    bor = (na & b2) | (na & bor) | (b2 & bor);
    // i = 1
    int d1 = a1 ^ b1 ^ bor;
    na = 1 - a1;
    bor = (na & b1) | (na & bor) | (b1 & bor);
    // i = 0 (MSB)
    int d0 = a0 ^ b0 ^ bor;
    na = 1 - a0;
    bor = (na & b0) | (na & bor) | (b0 & bor);

    v4f r;
    r[0] = (float)d0;
    r[1] = (float)d1;
    r[2] = (float)d2;
    r[3] = (float)d3;

    *((v4f*)res + i) = r;
    borrow_out[i] = (float)bor;
}

extern "C" void kernel_launch(void* const* d_in, const int* in_sizes, int n_in,
                              void* d_out, int out_size, void* d_ws, size_t ws_size,
                              hipStream_t stream)
{
    const float* A = (const float*)d_in[0];
    const float* B = (const float*)d_in[1];
    float* out = (float*)d_out;

    int n_rows = in_sizes[0] / 4;              // (N,4) -> N rows
    float* res = out;                          // first 4*N floats: diffs
    float* borrow = out + (size_t)n_rows * 4;  // last N floats: borrow

    int grid = (n_rows + BLOCK - 1) / BLOCK;
    Subtractor4Bit_kernel<<<grid, BLOCK, 0, stream>>>(A, B, res, borrow, n_rows);
}

// Round 5
// 316.278 us; speedup vs baseline: 1.1021x; 1.0150x over previous
//
#include <hip/hip_runtime.h>

// 4-bit ripple-borrow subtractor, one thread per row (flat R0 shape).
// A,B: (N,4) float32 with values in {0.0, 1.0}.
// Out: [ diffs (N,4) | borrow (N,1) ] flat float32.
// Index 3 is the LSB (reference loops i = 3..0).
//
// R5: R4 (NT loads — confirmed win: removed MALL thrash of the 268MB input
// sweep; kernel dropped 113 -> <99us, out of the profile top-5) + NT STORES.
// Theory: the 168MB write stream still allocates in MALL; every line is
// written back to HBM regardless (WRITE_SIZE == output size exactly), so
// allocation is pure churn. NT both sides = pure streaming, the regime where
// this chip measures 6.58-6.76 TB/s (harness fill kernels).
// R2-vs-R3 re-analysis: nt stores were ~neutral there; the RPT structure was
// the regression. Keep flat one-row-per-thread.

constexpr int BLOCK = 256;

typedef float v4f __attribute__((ext_vector_type(4)));

__global__ __launch_bounds__(BLOCK) void Subtractor4Bit_kernel(
    const float* __restrict__ A,
    const float* __restrict__ B,
    float* __restrict__ res,
    float* __restrict__ borrow_out,
    int n_rows)
{
    int i = blockIdx.x * BLOCK + threadIdx.x;
    if (i >= n_rows) return;

    v4f a = __builtin_nontemporal_load((const v4f*)A + i);
    v4f b = __builtin_nontemporal_load((const v4f*)B + i);

    // Convert to 0/1 ints (inputs are exactly 0.0f or 1.0f).
    int a0 = (a[0] != 0.0f), a1 = (a[1] != 0.0f), a2 = (a[2] != 0.0f), a3 = (a[3] != 0.0f);
    int b0 = (b[0] != 0.0f), b1 = (b[1] != 0.0f), b2 = (b[2] != 0.0f), b3 = (b[3] != 0.0f);

    int bor = 0;
    // i = 3 (LSB)
    int d3 = a3 ^ b3 ^ bor;
    int na = 1 - a3;
    bor = (na & b3) | (na & bor) | (b3 & bor);
    // i = 2
    int d2 = a2 ^ b2 ^ bor;
    na = 1 - a2;
    bor = (na & b2) | (na & bor) | (b2 & bor);
    // i = 1
    int d1 = a1 ^ b1 ^ bor;
    na = 1 - a1;
    bor = (na & b1) | (na & bor) | (b1 & bor);
    // i = 0 (MSB)
    int d0 = a0 ^ b0 ^ bor;
    na = 1 - a0;
    bor = (na & b0) | (na & bor) | (b0 & bor);

    v4f r;
    r[0] = (float)d0;
    r[1] = (float)d1;
    r[2] = (float)d2;
    r[3] = (float)d3;

    __builtin_nontemporal_store(r, (v4f*)res + i);
    __builtin_nontemporal_store((float)bor, borrow_out + i);
}

extern "C" void kernel_launch(void* const* d_in, const int* in_sizes, int n_in,
                              void* d_out, int out_size, void* d_ws, size_t ws_size,
                              hipStream_t stream)
{
    const float* A = (const float*)d_in[0];
    const float* B = (const float*)d_in[1];
    float* out = (float*)d_out;

    int n_rows = in_sizes[0] / 4;              // (N,4) -> N rows
    float* res = out;                          // first 4*N floats: diffs
    float* borrow = out + (size_t)n_rows * 4;  // last N floats: borrow

    int grid = (n_rows + BLOCK - 1) / BLOCK;
    Subtractor4Bit_kernel<<<grid, BLOCK, 0, stream>>>(A, B, res, borrow, n_rows);
}